// Round 6
// baseline (977.583 us; speedup 1.0000x reference)
//
#include <hip/hip_runtime.h>
#include <math.h>

#define Bb 64
#define Ss 512
#define Hh 256
#define Vv 32000
#define BS (Bb*Ss)      // 32768
#define NSTEPS 10

typedef __attribute__((ext_vector_type(8))) short bf16x8;   // 8 bf16 = 4 VGPR
typedef __attribute__((ext_vector_type(4))) float f32x4;    // MFMA C/D frag
typedef unsigned short u16;

#define MFMA(a,b,c) __builtin_amdgcn_mfma_f32_16x16x32_bf16((a),(b),(c),0,0,0)

__device__ __forceinline__ u16 f2bf(float f) {              // RNE
    unsigned u = __float_as_uint(f);
    u += 0x7fffu + ((u >> 16) & 1u);
    return (u16)(u >> 16);
}
__device__ __forceinline__ float bf2f(u16 h) {
    return __uint_as_float(((unsigned)h) << 16);
}
// physical Bbig column for (hcol j, gate g): fn&3 == gate
__device__ __forceinline__ int nmap(int j, int g) {
    return ((j >> 4) << 6) | (g << 4) | (j & 15);
}
#define GLL(src, dst) __builtin_amdgcn_global_load_lds( \
    (const __attribute__((address_space(1))) void*)(src), \
    (__attribute__((address_space(3))) void*)(dst), 16, 0, 0)

// ---------------------------------------------------------------------------
// prep: Bbig[nmap(j,g)][seg*256+k] = sum_k' W_edge[segmap][k][k'] * W_ih[g*256+j][k']
//       (+ W_hh[g*256+j][k] for seg==0 (self) and g in {r,z})
// seg order: 0=self(We[2]), 1=fwd h[s-1] (We[0]), 2=bwd h[s+1] (We[1])
// ---------------------------------------------------------------------------
__global__ __launch_bounds__(256)
void k_prep_big(const float* __restrict__ We, const float* __restrict__ Wih,
                const float* __restrict__ Whh, u16* __restrict__ Bbig) {
    __shared__ u16 Aps[64 * 32];
    __shared__ u16 Bps[64 * 32];
    const int p = blockIdx.y, seg = p / 3, g = p % 3;
    const int segmap0 = (seg == 0) ? 2 : (seg == 1 ? 0 : 1);
    const float* Wseg = We + segmap0 * 65536;
    const int kt = (blockIdx.x >> 2) * 64, jt = (blockIdx.x & 3) * 64;
    const int t = threadIdx.x;
    const int lane = t & 63, wid = t >> 6;
    const int wy = (wid >> 1) * 32, wx = (wid & 1) * 32;
    const int lr = lane & 15, hi = lane >> 4;

    f32x4 acc[2][2];
    #pragma unroll
    for (int a = 0; a < 2; ++a)
        #pragma unroll
        for (int b = 0; b < 2; ++b) acc[a][b] = 0.0f;

    for (int ks = 0; ks < 8; ++ks) {
        const int k0 = ks * 32;
        {
            int r = t >> 2, kc = t & 3;
            const float* sa = Wseg + (kt + r) * 256 + k0 + kc * 8;
            float4 a0 = *(const float4*)sa, a1 = *(const float4*)(sa + 4);
            bf16x8 va;
            va[0]=(short)f2bf(a0.x); va[1]=(short)f2bf(a0.y); va[2]=(short)f2bf(a0.z); va[3]=(short)f2bf(a0.w);
            va[4]=(short)f2bf(a1.x); va[5]=(short)f2bf(a1.y); va[6]=(short)f2bf(a1.z); va[7]=(short)f2bf(a1.w);
            ((bf16x8*)Aps)[r * 4 + (kc ^ (r & 3))] = va;
            const float* sb = Wih + (g * 256 + jt + r) * 256 + k0 + kc * 8;
            float4 b0 = *(const float4*)sb, b1 = *(const float4*)(sb + 4);
            bf16x8 vb;
            vb[0]=(short)f2bf(b0.x); vb[1]=(short)f2bf(b0.y); vb[2]=(short)f2bf(b0.z); vb[3]=(short)f2bf(b0.w);
            vb[4]=(short)f2bf(b1.x); vb[5]=(short)f2bf(b1.y); vb[6]=(short)f2bf(b1.z); vb[7]=(short)f2bf(b1.w);
            ((bf16x8*)Bps)[r * 4 + (kc ^ (r & 3))] = vb;
        }
        __syncthreads();
        bf16x8 af[2], bfv[2];
        #pragma unroll
        for (int f = 0; f < 2; ++f) {
            int ra = wy + f * 16 + lr;
            af[f]  = ((const bf16x8*)Aps)[ra * 4 + (hi ^ (ra & 3))];
            int rb = wx + f * 16 + lr;
            bfv[f] = ((const bf16x8*)Bps)[rb * 4 + (hi ^ (rb & 3))];
        }
        #pragma unroll
        for (int fm = 0; fm < 2; ++fm)
            #pragma unroll
            for (int fn = 0; fn < 2; ++fn)
                acc[fm][fn] = MFMA(af[fm], bfv[fn], acc[fm][fn]);
        __syncthreads();
    }
    #pragma unroll
    for (int fm = 0; fm < 2; ++fm)
        #pragma unroll
        for (int fn = 0; fn < 2; ++fn) {
            int kbase = kt + wy + fm * 16 + hi * 4;
            int j     = jt + wx + fn * 16 + lr;
            float4 wv = make_float4(0.f, 0.f, 0.f, 0.f);
            if (seg == 0 && g < 2)
                wv = *(const float4*)(Whh + (g * 256 + j) * 256 + kbase);
            ushort4 o;
            o.x = f2bf(acc[fm][fn][0] + wv.x);
            o.y = f2bf(acc[fm][fn][1] + wv.y);
            o.z = f2bf(acc[fm][fn][2] + wv.z);
            o.w = f2bf(acc[fm][fn][3] + wv.w);
            *(ushort4*)(Bbig + (size_t)nmap(j, g) * 768 + seg * 256 + kbase) = o;
        }
}

// gate-3 (HN) rows of Bbig: seg0 = Whn^T, seg1/2 = 0
__global__ __launch_bounds__(256)
void k_prep_hn(const float* __restrict__ Whh, u16* __restrict__ Bbig) {
    int j = blockIdx.x / 3;
    int k = (blockIdx.x % 3) * 256 + threadIdx.x;
    Bbig[(size_t)nmap(j, 3) * 768 + k] =
        (k < 256) ? f2bf(Whh[(512 + j) * 256 + k]) : (u16)0;
}

// bias table [3 classes][1024 physical cols]; class 0: s==0, 1: interior, 2: s==S-1
__global__ __launch_bounds__(256)
void k_prep_bias(const float* __restrict__ Wih, const float* __restrict__ b_edge,
                 const float* __restrict__ b_ih, const float* __restrict__ b_hh,
                 float* __restrict__ bias) {
    int id = blockIdx.x * 256 + threadIdx.x;       // 3072
    int c = id >> 10, n = id & 1023;
    int g = (n >> 4) & 3;
    int j = ((n >> 6) << 4) | (n & 15);
    float a;
    if (g == 3) {
        a = b_hh[512 + j];
    } else {
        a = b_ih[g * 256 + j] + (g < 2 ? b_hh[g * 256 + j] : 0.f);
        const float* wrow = Wih + (g * 256 + j) * 256;
        for (int k = 0; k < 256; ++k) {
            float eb = b_edge[512 + k] + (c != 0 ? b_edge[k] : 0.f)
                     + (c != 2 ? b_edge[256 + k] : 0.f);
            a += eb * wrow[k];
        }
    }
    bias[c * 1024 + n] = a;
}

__global__ __launch_bounds__(256)
void k_prep_zp(u16* __restrict__ zp) {
    zp[blockIdx.x * 256 + threadIdx.x] = 0;        // 512 u16
}

// ---------------------------------------------------------------------------
// h0 = emb[x] -> bf16
// ---------------------------------------------------------------------------
__global__ __launch_bounds__(256)
void k_embed(const int* __restrict__ x, const float* __restrict__ emb,
             u16* __restrict__ h) {
    int idx = blockIdx.x * 256 + threadIdx.x;       // 8-elem chunk id
    int row = idx >> 5, c8 = idx & 31;
    long long tok = x[row];
    const float4* e = reinterpret_cast<const float4*>(emb + tok * Hh + c8 * 8);
    float4 a = e[0], b = e[1];
    bf16x8 v;
    v[0]=(short)f2bf(a.x); v[1]=(short)f2bf(a.y); v[2]=(short)f2bf(a.z); v[3]=(short)f2bf(a.w);
    v[4]=(short)f2bf(b.x); v[5]=(short)f2bf(b.y); v[6]=(short)f2bf(b.z); v[7]=(short)f2bf(b.w);
    ((bf16x8*)h)[idx] = v;
}

// ---------------------------------------------------------------------------
// Fused step v4: GEMM M=32768 x N=1024 x K=768 + lane-parallel GRU epilogue.
// Structure = round-4 winner (single-buffer, GLL staging, syncthreads,
// conflict-free XOR swizzle, 48KB LDS -> multi-block/CU) with ONE change:
// wave tile 64x128 (4 waves/block, 256 thr, acc[4][8]) -> FLOP per LDS byte
// R = 32 -> 42.7. HN-gate MFMAs+B-frag-reads skipped for segs 1,2.
// ---------------------------------------------------------------------------
__global__ __launch_bounds__(256)
void k_step(const u16* __restrict__ hin, const u16* __restrict__ Bbig,
            const float* __restrict__ bias, const u16* __restrict__ zp,
            u16* __restrict__ hout) {
    __shared__ __attribute__((aligned(16))) u16 As[128 * 64];   // 16 KB
    __shared__ __attribute__((aligned(16))) u16 Bs[256 * 64];   // 32 KB
    const int t = threadIdx.x;
    const int lane = t & 63, wid = t >> 6;          // 4 waves
    const int rowBlk = blockIdx.y * 128;
    const int colBlk = blockIdx.x * 256;
    const int wy = wid >> 1, wx = wid & 1;          // 2 x 2 waves, tile 64x128
    const int lr = lane & 15, hi = lane >> 4;
    const int s0 = rowBlk & (Ss - 1);

    // --- B source pointers: 8 GLL/thread/iter, advance +64 elems/iter
    const u16* srcB[8];
    u16* dstB[8];
    #pragma unroll
    for (int j = 0; j < 8; ++j) {
        int c = t + j * 256;                        // 0..2047
        int r = c >> 3, kc = c & 7;
        srcB[j] = Bbig + (size_t)(colBlk + r) * 768 + ((kc ^ (r & 7)) << 3);
        dstB[j] = Bs + (size_t)(j * 256 + wid * 64) * 8;
    }
    // --- A dest (fixed); src recomputed per seg
    u16* dstA[4];
    int  rA[4], kcA[4];
    #pragma unroll
    for (int j = 0; j < 4; ++j) {
        int c = t + j * 256;                        // 0..1023
        rA[j] = c >> 3; kcA[j] = c & 7;
        dstA[j] = As + (size_t)(j * 256 + wid * 64) * 8;
    }

    f32x4 acc[4][8];
    #pragma unroll
    for (int a = 0; a < 4; ++a)
        #pragma unroll
        for (int b = 0; b < 8; ++b) acc[a][b] = 0.0f;

    #pragma unroll 1
    for (int seg = 0; seg < 3; ++seg) {
        const int d = (seg == 0) ? 0 : (seg == 1 ? -1 : 1);
        const u16* srcA[4];
        #pragma unroll
        for (int j = 0; j < 4; ++j) {
            int ss = s0 + rA[j] + d;
            srcA[j] = (ss >= 0 && ss < Ss)
                ? hin + (size_t)(rowBlk + rA[j] + d) * Hh + ((kcA[j] ^ (rA[j] & 7)) << 3)
                : zp;
        }
        #pragma unroll 1
        for (int k4 = 0; k4 < 4; ++k4) {
            #pragma unroll
            for (int j = 0; j < 4; ++j) { GLL(srcA[j], dstA[j]); srcA[j] += 64; }
            #pragma unroll
            for (int j = 0; j < 8; ++j) { GLL(srcB[j], dstB[j]); srcB[j] += 64; }
            __syncthreads();
            #pragma unroll
            for (int kk = 0; kk < 2; ++kk) {
                bf16x8 af[4];
                #pragma unroll
                for (int f = 0; f < 4; ++f) {
                    int ra = wy * 64 + f * 16 + lr;
                    af[f] = ((const bf16x8*)As)[ra * 8 + ((kk * 4 + hi) ^ (ra & 7))];
                }
                #pragma unroll
                for (int fq = 0; fq < 2; ++fq) {
                    bf16x8 bfv[4];
                    #pragma unroll
                    for (int f = 0; f < 4; ++f) {
                        if (seg != 0 && f == 3) continue;   // HN gate: segs 1,2 zero
                        int rb = wx * 128 + (fq * 4 + f) * 16 + lr;
                        bfv[f] = ((const bf16x8*)Bs)[rb * 8 + ((kk * 4 + hi) ^ (rb & 7))];
                    }
                    #pragma unroll
                    for (int fm = 0; fm < 4; ++fm)
                        #pragma unroll
                        for (int f = 0; f < 4; ++f)
                            if (seg == 0 || f < 3)
                                acc[fm][fq * 4 + f] = MFMA(af[fm], bfv[f], acc[fm][fq * 4 + f]);
                }
            }
            __syncthreads();
        }
    }
    // --- lane-parallel GRU epilogue: fn&3 == gate, lane owns (rows, one hcol)
    const int hq = (colBlk >> 2) + wx * 32;         // hcol base of this wave
    #pragma unroll
    for (int fm = 0; fm < 4; ++fm)
        #pragma unroll
        for (int fq = 0; fq < 2; ++fq)
            #pragma unroll
            for (int i = 0; i < 4; ++i) {
                int row = rowBlk + wy * 64 + fm * 16 + hi * 4 + i;
                int s = row & (Ss - 1);
                int cls = (s == 0) ? 0 : ((s == Ss - 1) ? 2 : 1);
                const float* bp = bias + cls * 1024 + colBlk + wx * 128 + fq * 64 + lr;
                float vr = acc[fm][fq * 4 + 0][i] + bp[0];
                float vz = acc[fm][fq * 4 + 1][i] + bp[16];
                float vn = acc[fm][fq * 4 + 2][i] + bp[32];
                float vh = acc[fm][fq * 4 + 3][i] + bp[48];
                float r = 1.f / (1.f + __expf(-vr));
                float z = 1.f / (1.f + __expf(-vz));
                float e = __expf(2.f * (vn + r * vh));
                float n = 1.f - 2.f / (e + 1.f);
                int hcol = hq + fq * 16 + lr;
                float hold = bf2f(hin[(size_t)row * Hh + hcol]);
                hout[(size_t)row * Hh + hcol] = f2bf(n + z * (hold - n));
            }
}

// ---------------------------------------------------------------------------
// out = last @ out_w.T + out_b via MFMA. M=64, N=32000, K=256.
// ---------------------------------------------------------------------------
__global__ __launch_bounds__(256)
void k_out(const u16* __restrict__ h, const float* __restrict__ out_w,
           const float* __restrict__ out_b, float* __restrict__ out) {
    __shared__ u16 As[64 * 256];
    const int t = threadIdx.x;
    const int lane = t & 63, wid = t >> 6;
    const int colBlk = blockIdx.x * 128;
    const int wc = wid * 32;
    const int lr = lane & 15, hi = lane >> 4;

    #pragma unroll
    for (int i = 0; i < 8; ++i) {                   // 2048 chunks
        int c = t + i * 256;
        int r = c >> 5, kc = c & 31;
        bf16x8 v = *(const bf16x8*)(h + ((size_t)(r * Ss + (Ss - 1))) * Hh + kc * 8);
        ((bf16x8*)As)[r * 32 + (kc ^ (r & 7))] = v;
    }
    __syncthreads();

    f32x4 acc[4][2];
    #pragma unroll
    for (int a = 0; a < 4; ++a) { acc[a][0] = 0.0f; acc[a][1] = 0.0f; }

    #pragma unroll
    for (int ks = 0; ks < 8; ++ks) {
        bf16x8 af[4];
        #pragma unroll
        for (int f = 0; f < 4; ++f) {
            int ra = f * 16 + lr;
            af[f] = ((const bf16x8*)As)[ra * 32 + ((ks * 4 + hi) ^ (ra & 7))];
        }
        #pragma unroll
        for (int fn = 0; fn < 2; ++fn) {
            int n = colBlk + wc + fn * 16 + lr;
            const float* wp = out_w + (size_t)n * 256 + ks * 32 + hi * 8;
            float4 w0 = *(const float4*)wp, w1 = *(const float4*)(wp + 4);
            bf16x8 vb;
            vb[0]=(short)f2bf(w0.x); vb[1]=(short)f2bf(w0.y); vb[2]=(short)f2bf(w0.z); vb[3]=(short)f2bf(w0.w);
            vb[4]=(short)f2bf(w1.x); vb[5]=(short)f2bf(w1.y); vb[6]=(short)f2bf(w1.z); vb[7]=(short)f2bf(w1.w);
            #pragma unroll
            for (int fm = 0; fm < 4; ++fm)
                acc[fm][fn] = MFMA(af[fm], vb, acc[fm][fn]);
        }
    }
    #pragma unroll
    for (int fm = 0; fm < 4; ++fm)
        #pragma unroll
        for (int fn = 0; fn < 2; ++fn)
            #pragma unroll
            for (int i = 0; i < 4; ++i) {
                int row = fm * 16 + hi * 4 + i;
                int col = colBlk + wc + fn * 16 + lr;
                out[(size_t)row * Vv + col] = acc[fm][fn][i] + out_b[col];
            }
}

// ---------------------------------------------------------------------------
extern "C" void kernel_launch(void* const* d_in, const int* in_sizes, int n_in,
                              void* d_out, int out_size, void* d_ws, size_t ws_size,
                              hipStream_t stream) {
    const int*   x      = (const int*)  d_in[0];
    const float* emb    = (const float*)d_in[1];
    const float* W_edge = (const float*)d_in[2];
    const float* b_edge = (const float*)d_in[3];
    const float* W_ih   = (const float*)d_in[4];
    const float* W_hh   = (const float*)d_in[5];
    const float* b_ih   = (const float*)d_in[6];
    const float* b_hh   = (const float*)d_in[7];
    const float* out_w  = (const float*)d_in[8];
    const float* out_b  = (const float*)d_in[9];
    float* out = (float*)d_out;

    // ws: hA | hB | Bbig (bf16 1024x768) | bias (f32 3x1024) | zp (512 u16)
    u16* hA   = (u16*)d_ws;
    u16* hB   = hA + (size_t)BS * Hh;
    u16* Bbig = hB + (size_t)BS * Hh;
    float* bias = (float*)(Bbig + (size_t)1024 * 768);
    u16* zp   = (u16*)(bias + 3 * 1024);

    k_prep_big <<<dim3(16, 9), 256, 0, stream>>>(W_edge, W_ih, W_hh, Bbig);
    k_prep_hn  <<<768, 256, 0, stream>>>(W_hh, Bbig);
    k_prep_bias<<<12, 256, 0, stream>>>(W_ih, b_edge, b_ih, b_hh, bias);
    k_prep_zp  <<<2, 256, 0, stream>>>(zp);
    k_embed    <<<BS * Hh / 8 / 256, 256, 0, stream>>>(x, emb, hA);

    u16* cur = hA;
    u16* nxt = hB;
    for (int step = 0; step < NSTEPS; ++step) {
        k_step<<<dim3(4, BS / 128), 256, 0, stream>>>(cur, Bbig, bias, zp, nxt);
        u16* tmp = cur; cur = nxt; nxt = tmp;
    }
    k_out<<<Vv / 128, 256, 0, stream>>>(cur, out_w, out_b, out);
}

// Round 7
// 571.219 us; speedup vs baseline: 1.7114x; 1.7114x over previous
//
#include <hip/hip_runtime.h>
#include <math.h>

#define Bb 64
#define Ss 512
#define Hh 256
#define Vv 32000
#define BS (Bb*Ss)      // 32768
#define NSTEPS 10

typedef __attribute__((ext_vector_type(8))) short bf16x8;   // 8 bf16 = 4 VGPR
typedef __attribute__((ext_vector_type(4))) float f32x4;    // MFMA C/D frag
typedef unsigned short u16;

#define MFMA(a,b,c) __builtin_amdgcn_mfma_f32_16x16x32_bf16((a),(b),(c),0,0,0)

__device__ __forceinline__ u16 f2bf(float f) {              // RNE
    unsigned u = __float_as_uint(f);
    u += 0x7fffu + ((u >> 16) & 1u);
    return (u16)(u >> 16);
}
__device__ __forceinline__ float bf2f(u16 h) {
    return __uint_as_float(((unsigned)h) << 16);
}
// physical Bbig column for (hcol j, gate g): fn-of-wave == gate
__device__ __forceinline__ int nmap(int j, int g) {
    return ((j >> 4) << 6) | (g << 4) | (j & 15);
}
#define GLL(src, dst) __builtin_amdgcn_global_load_lds( \
    (const __attribute__((address_space(1))) void*)(src), \
    (__attribute__((address_space(3))) void*)(dst), 16, 0, 0)

// ---------------------------------------------------------------------------
// prep: Bbig[nmap(j,g)][seg*256+k] = sum_k' W_edge[segmap][k][k'] * W_ih[g*256+j][k']
//       (+ W_hh[g*256+j][k] for seg==0 (self) and g in {r,z})
// seg order: 0=self(We[2]), 1=fwd h[s-1] (We[0]), 2=bwd h[s+1] (We[1])
// ---------------------------------------------------------------------------
__global__ __launch_bounds__(256)
void k_prep_big(const float* __restrict__ We, const float* __restrict__ Wih,
                const float* __restrict__ Whh, u16* __restrict__ Bbig) {
    __shared__ u16 Aps[64 * 32];
    __shared__ u16 Bps[64 * 32];
    const int p = blockIdx.y, seg = p / 3, g = p % 3;
    const int segmap0 = (seg == 0) ? 2 : (seg == 1 ? 0 : 1);
    const float* Wseg = We + segmap0 * 65536;
    const int kt = (blockIdx.x >> 2) * 64, jt = (blockIdx.x & 3) * 64;
    const int t = threadIdx.x;
    const int lane = t & 63, wid = t >> 6;
    const int wy = (wid >> 1) * 32, wx = (wid & 1) * 32;
    const int lr = lane & 15, hi = lane >> 4;

    f32x4 acc[2][2];
    #pragma unroll
    for (int a = 0; a < 2; ++a)
        #pragma unroll
        for (int b = 0; b < 2; ++b) acc[a][b] = 0.0f;

    for (int ks = 0; ks < 8; ++ks) {
        const int k0 = ks * 32;
        {
            int r = t >> 2, kc = t & 3;
            const float* sa = Wseg + (kt + r) * 256 + k0 + kc * 8;
            float4 a0 = *(const float4*)sa, a1 = *(const float4*)(sa + 4);
            bf16x8 va;
            va[0]=(short)f2bf(a0.x); va[1]=(short)f2bf(a0.y); va[2]=(short)f2bf(a0.z); va[3]=(short)f2bf(a0.w);
            va[4]=(short)f2bf(a1.x); va[5]=(short)f2bf(a1.y); va[6]=(short)f2bf(a1.z); va[7]=(short)f2bf(a1.w);
            ((bf16x8*)Aps)[r * 4 + (kc ^ (r & 3))] = va;
            const float* sb = Wih + (g * 256 + jt + r) * 256 + k0 + kc * 8;
            float4 b0 = *(const float4*)sb, b1 = *(const float4*)(sb + 4);
            bf16x8 vb;
            vb[0]=(short)f2bf(b0.x); vb[1]=(short)f2bf(b0.y); vb[2]=(short)f2bf(b0.z); vb[3]=(short)f2bf(b0.w);
            vb[4]=(short)f2bf(b1.x); vb[5]=(short)f2bf(b1.y); vb[6]=(short)f2bf(b1.z); vb[7]=(short)f2bf(b1.w);
            ((bf16x8*)Bps)[r * 4 + (kc ^ (r & 3))] = vb;
        }
        __syncthreads();
        bf16x8 af[2], bfv[2];
        #pragma unroll
        for (int f = 0; f < 2; ++f) {
            int ra = wy + f * 16 + lr;
            af[f]  = ((const bf16x8*)Aps)[ra * 4 + (hi ^ (ra & 3))];
            int rb = wx + f * 16 + lr;
            bfv[f] = ((const bf16x8*)Bps)[rb * 4 + (hi ^ (rb & 3))];
        }
        #pragma unroll
        for (int fm = 0; fm < 2; ++fm)
            #pragma unroll
            for (int fn = 0; fn < 2; ++fn)
                acc[fm][fn] = MFMA(af[fm], bfv[fn], acc[fm][fn]);
        __syncthreads();
    }
    #pragma unroll
    for (int fm = 0; fm < 2; ++fm)
        #pragma unroll
        for (int fn = 0; fn < 2; ++fn) {
            int kbase = kt + wy + fm * 16 + hi * 4;
            int j     = jt + wx + fn * 16 + lr;
            float4 wv = make_float4(0.f, 0.f, 0.f, 0.f);
            if (seg == 0 && g < 2)
                wv = *(const float4*)(Whh + (g * 256 + j) * 256 + kbase);
            ushort4 o;
            o.x = f2bf(acc[fm][fn][0] + wv.x);
            o.y = f2bf(acc[fm][fn][1] + wv.y);
            o.z = f2bf(acc[fm][fn][2] + wv.z);
            o.w = f2bf(acc[fm][fn][3] + wv.w);
            *(ushort4*)(Bbig + (size_t)nmap(j, g) * 768 + seg * 256 + kbase) = o;
        }
}

// gate-3 (HN) rows of Bbig: seg0 = Whn^T, seg1/2 = 0
__global__ __launch_bounds__(256)
void k_prep_hn(const float* __restrict__ Whh, u16* __restrict__ Bbig) {
    int j = blockIdx.x / 3;
    int k = (blockIdx.x % 3) * 256 + threadIdx.x;
    Bbig[(size_t)nmap(j, 3) * 768 + k] =
        (k < 256) ? f2bf(Whh[(512 + j) * 256 + k]) : (u16)0;
}

// bias table [3 classes][1024 physical cols]; class 0: s==0, 1: interior, 2: s==S-1
__global__ __launch_bounds__(256)
void k_prep_bias(const float* __restrict__ Wih, const float* __restrict__ b_edge,
                 const float* __restrict__ b_ih, const float* __restrict__ b_hh,
                 float* __restrict__ bias) {
    int id = blockIdx.x * 256 + threadIdx.x;       // 3072
    int c = id >> 10, n = id & 1023;
    int g = (n >> 4) & 3;
    int j = ((n >> 6) << 4) | (n & 15);
    float a;
    if (g == 3) {
        a = b_hh[512 + j];
    } else {
        a = b_ih[g * 256 + j] + (g < 2 ? b_hh[g * 256 + j] : 0.f);
        const float* wrow = Wih + (g * 256 + j) * 256;
        for (int k = 0; k < 256; ++k) {
            float eb = b_edge[512 + k] + (c != 0 ? b_edge[k] : 0.f)
                     + (c != 2 ? b_edge[256 + k] : 0.f);
            a += eb * wrow[k];
        }
    }
    bias[c * 1024 + n] = a;
}

__global__ __launch_bounds__(256)
void k_prep_zp(u16* __restrict__ zp) {
    zp[blockIdx.x * 256 + threadIdx.x] = 0;        // 512 u16
}

// ---------------------------------------------------------------------------
// h0 = emb[x] -> bf16
// ---------------------------------------------------------------------------
__global__ __launch_bounds__(256)
void k_embed(const int* __restrict__ x, const float* __restrict__ emb,
             u16* __restrict__ h) {
    int idx = blockIdx.x * 256 + threadIdx.x;       // 8-elem chunk id
    int row = idx >> 5, c8 = idx & 31;
    long long tok = x[row];
    const float4* e = reinterpret_cast<const float4*>(emb + tok * Hh + c8 * 8);
    float4 a = e[0], b = e[1];
    bf16x8 v;
    v[0]=(short)f2bf(a.x); v[1]=(short)f2bf(a.y); v[2]=(short)f2bf(a.z); v[3]=(short)f2bf(a.w);
    v[4]=(short)f2bf(b.x); v[5]=(short)f2bf(b.y); v[6]=(short)f2bf(b.z); v[7]=(short)f2bf(b.w);
    ((bf16x8*)h)[idx] = v;
}

// ---------------------------------------------------------------------------
// Fused step v5: GEMM M=32768 x N=1024 x K=768 + lane-parallel GRU epilogue.
// 256x256 tile, BK=64, 8 waves (2x4), wave tile 128x64 (acc[8][4]).
// Double-buffered A,B via global_load_lds (linear dest, pre-swizzled src,
// boundary rows -> zero page). Per K-tile: stages of tile t+1 issued in
// phases 0-1, 4 ds_read+MFMA phases on buffer t&1 with NO intra-tile
// barriers (read buf != write buf), ONE __syncthreads (vmcnt0+barrier)
// per tile -> drain lands ~3 phases after issue. HN-gate MFMAs skipped
// for segs 1,2. XCD-bijective block swizzle.
// ---------------------------------------------------------------------------
__global__ __launch_bounds__(512, 2)
void k_step(const u16* __restrict__ hin, const u16* __restrict__ Bbig,
            const float* __restrict__ bias, const u16* __restrict__ zp,
            u16* __restrict__ hout) {
    __shared__ __attribute__((aligned(16))) u16 As[2][2][128 * 64];  // 64 KB
    __shared__ __attribute__((aligned(16))) u16 Bs[2][2][128 * 64];  // 64 KB
    const int t = threadIdx.x;
    const int lane = t & 63, wid = t >> 6;
    // XCD-aware bijective swizzle: 512 blocks = 8 XCDs x 64
    const int swz = (blockIdx.x & 7) * 64 + (blockIdx.x >> 3);
    const int rowBlk = (swz >> 2) * 256;
    const int colBlk = (swz & 3) * 256;
    const int wy = wid >> 2, wx = wid & 3;          // 2 x 4 waves, tile 128x64
    const int lr = lane & 15, hi = lane >> 4;
    const int s0 = rowBlk & (Ss - 1);               // 0 or 256

    const int q   = t >> 3;                         // 0..63 (row in 64-group)
    const int off = ((t & 7) ^ (q & 7)) << 3;       // pre-swizzled elem offset
    const int xo  = lr & 7;                         // ds_read XOR operand

    // B persistent sources: rows q, q+64 (half0), q+128, q+192 (half1)
    const u16* pB[4];
    #pragma unroll
    for (int j = 0; j < 4; ++j)
        pB[j] = Bbig + (size_t)(colBlk + j * 64 + q) * 768 + off;

    f32x4 acc[8][4];
    #pragma unroll
    for (int a = 0; a < 8; ++a)
        #pragma unroll
        for (int b = 0; b < 4; ++b) acc[a][b] = 0.0f;

    // ---- prologue: stage tile 0 (seg0, d=0, k0=0) into buf 0
    #pragma unroll
    for (int h = 0; h < 2; ++h)
        #pragma unroll
        for (int i = 0; i < 2; ++i) {
            int rh = h * 128 + i * 64 + q;
            GLL(hin + (size_t)(rowBlk + rh) * Hh + off,
                &As[0][h][(i * 512 + wid * 64) * 8]);
            GLL(pB[h * 2 + i], &Bs[0][h][(i * 512 + wid * 64) * 8]);
        }
    #pragma unroll
    for (int j = 0; j < 4; ++j) pB[j] += 64;
    __syncthreads();

    // ---- main loop: 12 K-tiles (3 segs x 4), fully unrolled
    #pragma unroll
    for (int seg = 0; seg < 3; ++seg) {
        #pragma unroll
        for (int t4 = 0; t4 < 4; ++t4) {
            const int tt = seg * 4 + t4;
            const int b  = tt & 1, nb = b ^ 1;
            const int tn = tt + 1;
            const int segn = tn >> 2;
            const int dn   = (segn == 0) ? 0 : (segn == 1 ? -1 : 1);
            const int k0n  = (tn & 3) * 64;
            #pragma unroll
            for (int kk = 0; kk < 2; ++kk) {
                bf16x8 bf[4];
                #pragma unroll
                for (int mh = 0; mh < 2; ++mh) {
                    // --- stage next tile early: A at phase 0, B at phase 1
                    if (tt < 11 && kk == 0) {
                        if (mh == 0) {
                            #pragma unroll
                            for (int h = 0; h < 2; ++h)
                                #pragma unroll
                                for (int i = 0; i < 2; ++i) {
                                    int rh = h * 128 + i * 64 + q;
                                    int ss = s0 + rh + dn;
                                    const u16* src = (ss >= 0 && ss < Ss)
                                        ? hin + (size_t)(rowBlk + rh + dn) * Hh + k0n + off
                                        : zp;
                                    GLL(src, &As[nb][h][(i * 512 + wid * 64) * 8]);
                                }
                        } else {
                            #pragma unroll
                            for (int h = 0; h < 2; ++h)
                                #pragma unroll
                                for (int i = 0; i < 2; ++i)
                                    GLL(pB[h * 2 + i], &Bs[nb][h][(i * 512 + wid * 64) * 8]);
                            #pragma unroll
                            for (int j = 0; j < 4; ++j) pB[j] += 64;
                        }
                    }
                    // --- B fragments (read once per kk, reused across mh)
                    if (mh == 0) {
                        #pragma unroll
                        for (int f = 0; f < 4; ++f) {
                            if (seg != 0 && f == 3) continue;   // HN: segs 1,2 zero
                            int rwb = (wx & 1) * 64 + f * 16 + lr;
                            bf[f] = ((const bf16x8*)Bs[b][wx >> 1])
                                        [rwb * 8 + ((kk * 4 + hi) ^ xo)];
                        }
                    }
                    // --- A fragments
                    bf16x8 af[4];
                    #pragma unroll
                    for (int f = 0; f < 4; ++f) {
                        int rwa = mh * 64 + f * 16 + lr;
                        af[f] = ((const bf16x8*)As[b][wy])
                                    [rwa * 8 + ((kk * 4 + hi) ^ xo)];
                    }
                    // --- MFMA cluster
                    __builtin_amdgcn_s_setprio(1);
                    #pragma unroll
                    for (int fm = 0; fm < 4; ++fm)
                        #pragma unroll
                        for (int fn = 0; fn < 4; ++fn)
                            if (seg == 0 || fn < 3)
                                acc[mh * 4 + fm][fn] =
                                    MFMA(af[fm], bf[fn], acc[mh * 4 + fm][fn]);
                    __builtin_amdgcn_s_setprio(0);
                }
            }
            __syncthreads();   // once per tile: drain GLL (vmcnt0) + barrier
        }
    }

    // ---- lane-parallel GRU epilogue: fn == gate, lane owns (rows, one hcol)
    const int hq = (colBlk >> 2) + wx * 16;
    #pragma unroll
    for (int mf = 0; mf < 8; ++mf)
        #pragma unroll
        for (int i = 0; i < 4; ++i) {
            int row = rowBlk + wy * 128 + mf * 16 + hi * 4 + i;
            int s = row & (Ss - 1);
            int cls = (s == 0) ? 0 : ((s == Ss - 1) ? 2 : 1);
            const float* bp = bias + cls * 1024 + colBlk + wx * 64 + lr;
            float vr = acc[mf][0][i] + bp[0];
            float vz = acc[mf][1][i] + bp[16];
            float vn = acc[mf][2][i] + bp[32];
            float vh = acc[mf][3][i] + bp[48];
            float r = 1.f / (1.f + __expf(-vr));
            float z = 1.f / (1.f + __expf(-vz));
            float e = __expf(2.f * (vn + r * vh));
            float n = 1.f - 2.f / (e + 1.f);
            int hcol = hq + lr;
            float hold = bf2f(hin[(size_t)row * Hh + hcol]);
            hout[(size_t)row * Hh + hcol] = f2bf(n + z * (hold - n));
        }
}

// ---------------------------------------------------------------------------
// out = last @ out_w.T + out_b via MFMA. M=64, N=32000, K=256.
// ---------------------------------------------------------------------------
__global__ __launch_bounds__(256)
void k_out(const u16* __restrict__ h, const float* __restrict__ out_w,
           const float* __restrict__ out_b, float* __restrict__ out) {
    __shared__ u16 As[64 * 256];
    const int t = threadIdx.x;
    const int lane = t & 63, wid = t >> 6;
    const int colBlk = blockIdx.x * 128;
    const int wc = wid * 32;
    const int lr = lane & 15, hi = lane >> 4;

    #pragma unroll
    for (int i = 0; i < 8; ++i) {                   // 2048 chunks
        int c = t + i * 256;
        int r = c >> 5, kc = c & 31;
        bf16x8 v = *(const bf16x8*)(h + ((size_t)(r * Ss + (Ss - 1))) * Hh + kc * 8);
        ((bf16x8*)As)[r * 32 + (kc ^ (r & 7))] = v;
    }
    __syncthreads();

    f32x4 acc[4][2];
    #pragma unroll
    for (int a = 0; a < 4; ++a) { acc[a][0] = 0.0f; acc[a][1] = 0.0f; }

    #pragma unroll
    for (int ks = 0; ks < 8; ++ks) {
        bf16x8 af[4];
        #pragma unroll
        for (int f = 0; f < 4; ++f) {
            int ra = f * 16 + lr;
            af[f] = ((const bf16x8*)As)[ra * 32 + ((ks * 4 + hi) ^ (ra & 7))];
        }
        #pragma unroll
        for (int fn = 0; fn < 2; ++fn) {
            int n = colBlk + wc + fn * 16 + lr;
            const float* wp = out_w + (size_t)n * 256 + ks * 32 + hi * 8;
            float4 w0 = *(const float4*)wp, w1 = *(const float4*)(wp + 4);
            bf16x8 vb;
            vb[0]=(short)f2bf(w0.x); vb[1]=(short)f2bf(w0.y); vb[2]=(short)f2bf(w0.z); vb[3]=(short)f2bf(w0.w);
            vb[4]=(short)f2bf(w1.x); vb[5]=(short)f2bf(w1.y); vb[6]=(short)f2bf(w1.z); vb[7]=(short)f2bf(w1.w);
            #pragma unroll
            for (int fm = 0; fm < 4; ++fm)
                acc[fm][fn] = MFMA(af[fm], vb, acc[fm][fn]);
        }
    }
    #pragma unroll
    for (int fm = 0; fm < 4; ++fm)
        #pragma unroll
        for (int fn = 0; fn < 2; ++fn)
            #pragma unroll
            for (int i = 0; i < 4; ++i) {
                int row = fm * 16 + hi * 4 + i;
                int col = colBlk + wc + fn * 16 + lr;
                out[(size_t)row * Vv + col] = acc[fm][fn][i] + out_b[col];
            }
}

// ---------------------------------------------------------------------------
extern "C" void kernel_launch(void* const* d_in, const int* in_sizes, int n_in,
                              void* d_out, int out_size, void* d_ws, size_t ws_size,
                              hipStream_t stream) {
    const int*   x      = (const int*)  d_in[0];
    const float* emb    = (const float*)d_in[1];
    const float* W_edge = (const float*)d_in[2];
    const float* b_edge = (const float*)d_in[3];
    const float* W_ih   = (const float*)d_in[4];
    const float* W_hh   = (const float*)d_in[5];
    const float* b_ih   = (const float*)d_in[6];
    const float* b_hh   = (const float*)d_in[7];
    const float* out_w  = (const float*)d_in[8];
    const float* out_b  = (const float*)d_in[9];
    float* out = (float*)d_out;

    // ws: hA | hB | Bbig (bf16 1024x768) | bias (f32 3x1024) | zp (512 u16)
    u16* hA   = (u16*)d_ws;
    u16* hB   = hA + (size_t)BS * Hh;
    u16* Bbig = hB + (size_t)BS * Hh;
    float* bias = (float*)(Bbig + (size_t)1024 * 768);
    u16* zp   = (u16*)(bias + 3 * 1024);

    k_prep_big <<<dim3(16, 9), 256, 0, stream>>>(W_edge, W_ih, W_hh, Bbig);
    k_prep_hn  <<<768, 256, 0, stream>>>(W_hh, Bbig);
    k_prep_bias<<<12, 256, 0, stream>>>(W_ih, b_edge, b_ih, b_hh, bias);
    k_prep_zp  <<<2, 256, 0, stream>>>(zp);
    k_embed    <<<BS * Hh / 8 / 256, 256, 0, stream>>>(x, emb, hA);

    u16* cur = hA;
    u16* nxt = hB;
    for (int step = 0; step < NSTEPS; ++step) {
        k_step<<<512, 512, 0, stream>>>(cur, Bbig, bias, zp, nxt);
        u16* tmp = cur; cur = nxt; nxt = tmp;
    }
    k_out<<<Vv / 128, 256, 0, stream>>>(cur, out_w, out_b, out);
}